// Round 1
// 315.542 us; speedup vs baseline: 1.2390x; 1.2390x over previous
//
#include <hip/hip_runtime.h>

#define DIM 64
#define GPW 4    // 16-row groups per wave in gemm
#define BSHIFT 9
#define BSPAN 512      // nodes per bucket
#define MAXNB 512      // max buckets (N <= 262144; here N=200000 -> NB=391)

typedef __attribute__((ext_vector_type(8))) __bf16 bf16x8;
typedef __attribute__((ext_vector_type(4))) float f32x4;

__device__ __forceinline__ f32x4 mfma16(bf16x8 a, bf16x8 b, f32x4 c) {
    return __builtin_amdgcn_mfma_f32_16x16x32_bf16(a, b, c, 0, 0, 0);
}

// ---------- hierarchical CSR build (bucket -> node counting sort) ----------

__global__ void zerob_kernel(int* __restrict__ b) { b[threadIdx.x] = 0; }

// P1: bucket histogram via LDS; ~100K global atomics instead of 1.2M random.
__global__ __launch_bounds__(512) void bucket_count_kernel(
    const int* __restrict__ ei, int* __restrict__ bcnt, int E_, int NB) {
    __shared__ int hist[MAXNB];
    int tid = threadIdx.x;
    for (int i = tid; i < NB; i += 512) hist[i] = 0;
    __syncthreads();
    int chunk = (E_ + gridDim.x - 1) / gridDim.x;
    int e0 = blockIdx.x * chunk, e1 = min(E_, e0 + chunk);
    for (int e = e0 + tid; e < e1; e += 512)
        atomicAdd(&hist[ei[E_ + e] >> BSHIFT], 1);
    __syncthreads();
    for (int i = tid; i < NB; i += 512)
        if (hist[i]) atomicAdd(&bcnt[i], hist[i]);
}

// P2: exclusive scan of bucket counts (NB <= 512); also seals rowptr[N]=E.
__global__ __launch_bounds__(512) void bucket_scan_kernel(
    const int* __restrict__ bcnt, int* __restrict__ bptr, int* __restrict__ bcur,
    int* __restrict__ rowptr, int NB, int N_, int E_) {
    __shared__ int sm[512];
    int tid = threadIdx.x;
    int v = (tid < NB) ? bcnt[tid] : 0;
    sm[tid] = v;
    __syncthreads();
    for (int off = 1; off < 512; off <<= 1) {
        int t = 0;
        if (tid >= off) t = sm[tid - off];
        __syncthreads();
        if (tid >= off) sm[tid] += t;
        __syncthreads();
    }
    if (tid < NB) {
        int ex = sm[tid] - v;
        bptr[tid] = ex;
        bcur[tid] = ex;
    }
    if (tid == 0) { bptr[NB] = E_; rowptr[N_] = E_; }
}

// P3: coarse scatter into bucket-contiguous spans. Two passes per block:
// LDS hist -> one global atomicAdd per (block,bucket) -> append via LDS
// cursors. Block's writes per bucket are contiguous ascending => cache
// lines fill before eviction (kills the 17x write amplification of the
// old random fill). Edge packed as (src<<9)|(dst&511) in one u32.
__global__ __launch_bounds__(512) void scatter_kernel(
    const int* __restrict__ ei, int* __restrict__ bcur,
    unsigned* __restrict__ packed, int E_, int NB) {
    __shared__ int h[MAXNB];
    int tid = threadIdx.x;
    int chunk = (E_ + gridDim.x - 1) / gridDim.x;
    int e0 = blockIdx.x * chunk, e1 = min(E_, e0 + chunk);
    for (int i = tid; i < NB; i += 512) h[i] = 0;
    __syncthreads();
    for (int e = e0 + tid; e < e1; e += 512)
        atomicAdd(&h[ei[E_ + e] >> BSHIFT], 1);
    __syncthreads();
    for (int i = tid; i < NB; i += 512) {
        int c = h[i];
        h[i] = c ? atomicAdd(&bcur[i], c) : 0;
    }
    __syncthreads();
    for (int e = e0 + tid; e < e1; e += 512) {
        int s = ei[e], d = ei[E_ + e];
        int b = d >> BSHIFT;
        int pos = atomicAdd(&h[b], 1);   // LDS cursor holding global base
        packed[pos] = ((unsigned)s << BSHIFT) | (unsigned)(d & (BSPAN - 1));
    }
}

// P4: per-bucket fine counting sort (one block per bucket). The bucket's
// edge span (~12 KB) is L1/L2-resident, so the random within-bucket
// scatter costs nothing at HBM. Also emits rowptr + dinv (replaces
// count/scanA/scanB/scanC of the old pipeline).
__global__ __launch_bounds__(256) void bucket_sort_kernel(
    const unsigned* __restrict__ packed, const int* __restrict__ bptr,
    int* __restrict__ rowptr, int* __restrict__ srcs,
    float* __restrict__ dinv, int N_) {
    __shared__ int cnt[BSPAN];
    __shared__ int sc[256];
    int tid = threadIdx.x;
    int b = blockIdx.x;
    int beg = bptr[b], end = bptr[b + 1];
    int node0 = b << BSHIFT;
    int nn = min(BSPAN, N_ - node0);
    cnt[tid] = 0; cnt[tid + 256] = 0;
    __syncthreads();
    for (int i = beg + tid; i < end; i += 256)
        atomicAdd(&cnt[packed[i] & (BSPAN - 1)], 1);
    __syncthreads();
    int degA = cnt[tid], degB = cnt[tid + 256];
    int a0 = cnt[2 * tid], a1 = cnt[2 * tid + 1];
    if (tid < nn) dinv[node0 + tid] = rsqrtf((float)(1 + degA));
    if (tid + 256 < nn) dinv[node0 + tid + 256] = rsqrtf((float)(1 + degB));
    // exclusive scan of cnt[0..511]: thread owns pair (2t, 2t+1)
    int tot = a0 + a1;
    sc[tid] = tot;
    __syncthreads();
    for (int off = 1; off < 256; off <<= 1) {
        int t = 0;
        if (tid >= off) t = sc[tid - off];
        __syncthreads();
        if (tid >= off) sc[tid] += t;
        __syncthreads();
    }
    int ex = sc[tid] - tot;
    cnt[2 * tid] = ex;
    cnt[2 * tid + 1] = ex + a0;
    __syncthreads();
    if (tid < nn) rowptr[node0 + tid] = beg + cnt[tid];
    if (tid + 256 < nn) rowptr[node0 + tid + 256] = beg + cnt[tid + 256];
    __syncthreads();   // rowptr reads done before cursor mutation
    for (int i = beg + tid; i < end; i += 256) {
        unsigned p = packed[i];
        int pos = atomicAdd(&cnt[p & (BSPAN - 1)], 1);
        srcs[beg + pos] = (int)(p >> BSHIFT);
    }
}

// ---------- layer kernels (unchanged) ----------

// h'(bf16) = (x @ W) * dinv[row].   MFMA 16x16x32 bf16.
template <bool BF16IN>
__global__ __launch_bounds__(256) void gemm_kernel(
    const void* __restrict__ xa_, const void* __restrict__ xb_, int split,
    const float* __restrict__ W, const float* __restrict__ dinv,
    __bf16* __restrict__ h, int n, int ngroups) {
    int lane = threadIdx.x & 63;
    int q = lane >> 4, t = lane & 15;
    int wv = __builtin_amdgcn_readfirstlane(threadIdx.x >> 6);
    int g0 = (blockIdx.x * 4 + wv) * GPW;
    if (g0 >= ngroups) return;

    bf16x8 Bf[4][2];
#pragma unroll
    for (int nt = 0; nt < 4; ++nt)
#pragma unroll
        for (int kt = 0; kt < 2; ++kt) {
            bf16x8 f;
#pragma unroll
            for (int j = 0; j < 8; ++j)
                f[j] = (__bf16)W[(kt * 32 + q * 8 + j) * DIM + nt * 16 + t];
            Bf[nt][kt] = f;
        }

    auto loadA = [&](int r0, f32x4* raw) {
        int row = r0 + t;
        if (row >= n) row = n - 1;
        if constexpr (BF16IN) {
            const __bf16* xr = (const __bf16*)xa_ + (size_t)row * DIM;
            raw[0] = *(const f32x4*)(xr + q * 8);
            raw[1] = *(const f32x4*)(xr + 32 + q * 8);
        } else {
            const float* xr = (row < split)
                ? ((const float*)xa_ + (size_t)row * DIM)
                : ((const float*)xb_ + (size_t)(row - split) * DIM);
            raw[0] = *(const f32x4*)(xr + q * 8);
            raw[1] = *(const f32x4*)(xr + q * 8 + 4);
            raw[2] = *(const f32x4*)(xr + 32 + q * 8);
            raw[3] = *(const f32x4*)(xr + 32 + q * 8 + 4);
        }
    };

    f32x4 cur[4];
    loadA(g0 * 16, cur);

#pragma unroll 1
    for (int gi = 0; gi < GPW; ++gi) {
        int g = g0 + gi;
        if (g >= ngroups) break;
        int r0 = g * 16;
        f32x4 nxt[4];
        bool pf = (gi + 1 < GPW) && (g + 1 < ngroups);
        if (pf) loadA(r0 + 16, nxt);

        bf16x8 A0, A1;
        if constexpr (BF16IN) {
            A0 = __builtin_bit_cast(bf16x8, cur[0]);
            A1 = __builtin_bit_cast(bf16x8, cur[1]);
        } else {
#pragma unroll
            for (int j = 0; j < 4; ++j) {
                A0[j] = (__bf16)cur[0][j]; A0[j + 4] = (__bf16)cur[1][j];
                A1[j] = (__bf16)cur[2][j]; A1[j + 4] = (__bf16)cur[3][j];
            }
        }

        f32x4 z = {0.f, 0.f, 0.f, 0.f};
        f32x4 acc[4];
#pragma unroll
        for (int nt = 0; nt < 4; ++nt)
            acc[nt] = mfma16(A1, Bf[nt][1], mfma16(A0, Bf[nt][0], z));

        f32x4 d4 = *(const f32x4*)(dinv + r0 + q * 4);
#pragma unroll
        for (int nt = 0; nt < 4; ++nt)
#pragma unroll
            for (int reg = 0; reg < 4; ++reg) {
                int row = r0 + q * 4 + reg;
                if (row < n)
                    h[(size_t)row * DIM + nt * 16 + t] =
                        (__bf16)(acc[nt][reg] * d4[reg]);
            }
#pragma unroll
        for (int i = 0; i < 4; ++i) cur[i] = nxt[i];
    }
}

// out[node] = b + dinv[node] * (h'[node] + sum_s h'[s])
template <typename OutT>
__global__ __launch_bounds__(256) void agg_kernel(
    const int* __restrict__ rowptr, const int* __restrict__ srcs,
    const __bf16* __restrict__ h, const float* __restrict__ bias,
    const float* __restrict__ dinv, OutT* __restrict__ out, int n) {
    int lane = threadIdx.x & 63;
    int node = blockIdx.x * 4 + __builtin_amdgcn_readfirstlane(threadIdx.x >> 6);
    if (node >= n) return;
    int beg = rowptr[node], end = rowptr[node + 1];
    float acc = (float)h[(size_t)node * DIM + lane];   // self-loop row, coalesced
    float a0 = 0.f, a1 = 0.f, a2 = 0.f, a3 = 0.f;
    int i = beg;
    for (; i + 4 <= end; i += 4) {
        int s0 = srcs[i], s1 = srcs[i + 1], s2 = srcs[i + 2], s3 = srcs[i + 3];
        a0 += (float)h[(size_t)s0 * DIM + lane];
        a1 += (float)h[(size_t)s1 * DIM + lane];
        a2 += (float)h[(size_t)s2 * DIM + lane];
        a3 += (float)h[(size_t)s3 * DIM + lane];
    }
    for (; i < end; ++i)
        acc += (float)h[(size_t)srcs[i] * DIM + lane];
    acc += (a0 + a1) + (a2 + a3);
    float res = fmaf(dinv[node], acc, bias[lane]);
    out[(size_t)node * DIM + lane] = (OutT)res;
}

static inline size_t align16(size_t x) { return (x + 15) & ~(size_t)15; }

extern "C" void kernel_launch(void* const* d_in, const int* in_sizes, int n_in,
                              void* d_out, int out_size, void* d_ws, size_t ws_size,
                              hipStream_t stream) {
    const int* ei         = (const int*)d_in[0];
    const float* user_emb = (const float*)d_in[1];
    const float* item_emb = (const float*)d_in[2];
    const float* W1 = (const float*)d_in[3];
    const float* b1 = (const float*)d_in[4];
    const float* W2 = (const float*)d_in[5];
    const float* b2 = (const float*)d_in[6];
    float* out = (float*)d_out;

    const int E_ = in_sizes[0] / 2;
    const int NU = in_sizes[1] / DIM;
    const int NI = in_sizes[2] / DIM;
    const int N_ = NU + NI;
    const int NB = (N_ + BSPAN - 1) >> BSHIFT;   // 391 for N=200000 (<= MAXNB)

    // workspace layout (16B-aligned)
    char* p = (char*)d_ws;
    int* srcs   = (int*)p;                   p += align16((size_t)E_ * 4);
    __bf16* h   = (__bf16*)p;                p += align16((size_t)N_ * DIM * 2);
    __bf16* t1  = (__bf16*)p;                p += align16((size_t)N_ * DIM * 2);
    float* dinv = (float*)p;                 p += align16((size_t)N_ * 4);
    int* rowptr = (int*)p;                   p += align16((size_t)(N_ + 1) * 4);
    int* bcnt   = (int*)p;                   p += align16((size_t)MAXNB * 4);
    int* bptr   = (int*)p;                   p += align16((size_t)(MAXNB + 1) * 4);
    int* bcur   = (int*)p;                   p += align16((size_t)MAXNB * 4);
    // packed edge buffer aliases t1: fully consumed by bucket_sort before
    // agg1 writes t1 (src<<9|dstlow fits u32 since N < 2^18 * ... < 2^23).
    unsigned* packed = (unsigned*)t1;

    zerob_kernel<<<1, MAXNB, 0, stream>>>(bcnt);
    bucket_count_kernel<<<256, 512, 0, stream>>>(ei, bcnt, E_, NB);
    bucket_scan_kernel<<<1, 512, 0, stream>>>(bcnt, bptr, bcur, rowptr, NB, N_, E_);
    scatter_kernel<<<256, 512, 0, stream>>>(ei, bcur, packed, E_, NB);
    bucket_sort_kernel<<<NB, 256, 0, stream>>>(packed, bptr, rowptr, srcs, dinv, N_);

    int NG = (N_ + 15) / 16;                       // 16-row groups
    int gblocks = (NG + 4 * GPW - 1) / (4 * GPW);  // 4 waves/block
    int ablocks = (N_ + 3) / 4;

    // layer 1
    gemm_kernel<false><<<gblocks, 256, 0, stream>>>(user_emb, item_emb, NU,
                                                    W1, dinv, h, N_, NG);
    agg_kernel<__bf16><<<ablocks, 256, 0, stream>>>(rowptr, srcs, h, b1, dinv, t1, N_);
    // layer 2
    gemm_kernel<true><<<gblocks, 256, 0, stream>>>(t1, t1, N_,
                                                   W2, dinv, h, N_, NG);
    agg_kernel<float><<<ablocks, 256, 0, stream>>>(rowptr, srcs, h, b2, dinv, out, N_);
}

// Round 2
// 302.511 us; speedup vs baseline: 1.2924x; 1.0431x over previous
//
#include <hip/hip_runtime.h>

#define DIM 64
#define GPW 4    // 16-row groups per wave in gemm
#define BSHIFT 9
#define BSPAN 512      // nodes per bucket
#define MAXNB 512      // max buckets (N <= 262144; here N=200000 -> NB=391)

typedef __attribute__((ext_vector_type(8))) __bf16 bf16x8;
typedef __attribute__((ext_vector_type(4))) __bf16 bf16x4;
typedef __attribute__((ext_vector_type(4))) float f32x4;

__device__ __forceinline__ f32x4 mfma16(bf16x8 a, bf16x8 b, f32x4 c) {
    return __builtin_amdgcn_mfma_f32_16x16x32_bf16(a, b, c, 0, 0, 0);
}

__device__ __forceinline__ float bf2f(unsigned short u) {
    return __uint_as_float((unsigned)u << 16);
}

// ---------- hierarchical CSR build (bucket -> node counting sort) ----------

__global__ void zerob_kernel(int* __restrict__ b) { b[threadIdx.x] = 0; }

// P1: bucket histogram via LDS; ~100K global atomics instead of 1.2M random.
__global__ __launch_bounds__(512) void bucket_count_kernel(
    const int* __restrict__ ei, int* __restrict__ bcnt, int E_, int NB) {
    __shared__ int hist[MAXNB];
    int tid = threadIdx.x;
    for (int i = tid; i < NB; i += 512) hist[i] = 0;
    __syncthreads();
    int chunk = (E_ + gridDim.x - 1) / gridDim.x;
    int e0 = blockIdx.x * chunk, e1 = min(E_, e0 + chunk);
    for (int e = e0 + tid; e < e1; e += 512)
        atomicAdd(&hist[ei[E_ + e] >> BSHIFT], 1);
    __syncthreads();
    for (int i = tid; i < NB; i += 512)
        if (hist[i]) atomicAdd(&bcnt[i], hist[i]);
}

// P2: exclusive scan of bucket counts (NB <= 512); also seals rowptr[N]=E.
__global__ __launch_bounds__(512) void bucket_scan_kernel(
    const int* __restrict__ bcnt, int* __restrict__ bptr, int* __restrict__ bcur,
    int* __restrict__ rowptr, int NB, int N_, int E_) {
    __shared__ int sm[512];
    int tid = threadIdx.x;
    int v = (tid < NB) ? bcnt[tid] : 0;
    sm[tid] = v;
    __syncthreads();
    for (int off = 1; off < 512; off <<= 1) {
        int t = 0;
        if (tid >= off) t = sm[tid - off];
        __syncthreads();
        if (tid >= off) sm[tid] += t;
        __syncthreads();
    }
    if (tid < NB) {
        int ex = sm[tid] - v;
        bptr[tid] = ex;
        bcur[tid] = ex;
    }
    if (tid == 0) { bptr[NB] = E_; rowptr[N_] = E_; }
}

// P3: coarse scatter into bucket-contiguous spans. Two passes per block:
// LDS hist -> one global atomicAdd per (block,bucket) -> append via LDS
// cursors. Block's writes per bucket are contiguous ascending => cache
// lines fill before eviction. Edge packed as (src<<9)|(dst&511) in one u32.
__global__ __launch_bounds__(512) void scatter_kernel(
    const int* __restrict__ ei, int* __restrict__ bcur,
    unsigned* __restrict__ packed, int E_, int NB) {
    __shared__ int h[MAXNB];
    int tid = threadIdx.x;
    int chunk = (E_ + gridDim.x - 1) / gridDim.x;
    int e0 = blockIdx.x * chunk, e1 = min(E_, e0 + chunk);
    for (int i = tid; i < NB; i += 512) h[i] = 0;
    __syncthreads();
    for (int e = e0 + tid; e < e1; e += 512)
        atomicAdd(&h[ei[E_ + e] >> BSHIFT], 1);
    __syncthreads();
    for (int i = tid; i < NB; i += 512) {
        int c = h[i];
        h[i] = c ? atomicAdd(&bcur[i], c) : 0;
    }
    __syncthreads();
    for (int e = e0 + tid; e < e1; e += 512) {
        int s = ei[e], d = ei[E_ + e];
        int b = d >> BSHIFT;
        int pos = atomicAdd(&h[b], 1);   // LDS cursor holding global base
        packed[pos] = ((unsigned)s << BSHIFT) | (unsigned)(d & (BSPAN - 1));
    }
}

// P4: per-bucket fine counting sort (one block per bucket). Bucket's edge
// span (~12 KB) is L1/L2-resident; random within-bucket scatter costs
// nothing at HBM. Also emits rowptr + dinv.
__global__ __launch_bounds__(256) void bucket_sort_kernel(
    const unsigned* __restrict__ packed, const int* __restrict__ bptr,
    int* __restrict__ rowptr, int* __restrict__ srcs,
    float* __restrict__ dinv, int N_) {
    __shared__ int cnt[BSPAN];
    __shared__ int sc[256];
    int tid = threadIdx.x;
    int b = blockIdx.x;
    int beg = bptr[b], end = bptr[b + 1];
    int node0 = b << BSHIFT;
    int nn = min(BSPAN, N_ - node0);
    cnt[tid] = 0; cnt[tid + 256] = 0;
    __syncthreads();
    for (int i = beg + tid; i < end; i += 256)
        atomicAdd(&cnt[packed[i] & (BSPAN - 1)], 1);
    __syncthreads();
    int degA = cnt[tid], degB = cnt[tid + 256];
    int a0 = cnt[2 * tid], a1 = cnt[2 * tid + 1];
    if (tid < nn) dinv[node0 + tid] = rsqrtf((float)(1 + degA));
    if (tid + 256 < nn) dinv[node0 + tid + 256] = rsqrtf((float)(1 + degB));
    // exclusive scan of cnt[0..511]: thread owns pair (2t, 2t+1)
    int tot = a0 + a1;
    sc[tid] = tot;
    __syncthreads();
    for (int off = 1; off < 256; off <<= 1) {
        int t = 0;
        if (tid >= off) t = sc[tid - off];
        __syncthreads();
        if (tid >= off) sc[tid] += t;
        __syncthreads();
    }
    int ex = sc[tid] - tot;
    cnt[2 * tid] = ex;
    cnt[2 * tid + 1] = ex + a0;
    __syncthreads();
    if (tid < nn) rowptr[node0 + tid] = beg + cnt[tid];
    if (tid + 256 < nn) rowptr[node0 + tid + 256] = beg + cnt[tid + 256];
    __syncthreads();   // rowptr reads done before cursor mutation
    for (int i = beg + tid; i < end; i += 256) {
        unsigned p = packed[i];
        int pos = atomicAdd(&cnt[p & (BSPAN - 1)], 1);
        srcs[beg + pos] = (int)(p >> BSHIFT);
    }
}

// ---------- layer kernels ----------

// h'(bf16) = (x @ W) * dinv[row].   MFMA 16x16x32 bf16.
template <bool BF16IN>
__global__ __launch_bounds__(256) void gemm_kernel(
    const void* __restrict__ xa_, const void* __restrict__ xb_, int split,
    const float* __restrict__ W, const float* __restrict__ dinv,
    __bf16* __restrict__ h, int n, int ngroups) {
    int lane = threadIdx.x & 63;
    int q = lane >> 4, t = lane & 15;
    int wv = __builtin_amdgcn_readfirstlane(threadIdx.x >> 6);
    int g0 = (blockIdx.x * 4 + wv) * GPW;
    if (g0 >= ngroups) return;

    bf16x8 Bf[4][2];
#pragma unroll
    for (int nt = 0; nt < 4; ++nt)
#pragma unroll
        for (int kt = 0; kt < 2; ++kt) {
            bf16x8 f;
#pragma unroll
            for (int j = 0; j < 8; ++j)
                f[j] = (__bf16)W[(kt * 32 + q * 8 + j) * DIM + nt * 16 + t];
            Bf[nt][kt] = f;
        }

    auto loadA = [&](int r0, f32x4* raw) {
        int row = r0 + t;
        if (row >= n) row = n - 1;
        if constexpr (BF16IN) {
            const __bf16* xr = (const __bf16*)xa_ + (size_t)row * DIM;
            raw[0] = *(const f32x4*)(xr + q * 8);
            raw[1] = *(const f32x4*)(xr + 32 + q * 8);
        } else {
            const float* xr = (row < split)
                ? ((const float*)xa_ + (size_t)row * DIM)
                : ((const float*)xb_ + (size_t)(row - split) * DIM);
            raw[0] = *(const f32x4*)(xr + q * 8);
            raw[1] = *(const f32x4*)(xr + q * 8 + 4);
            raw[2] = *(const f32x4*)(xr + 32 + q * 8);
            raw[3] = *(const f32x4*)(xr + 32 + q * 8 + 4);
        }
    };

    f32x4 cur[4];
    loadA(g0 * 16, cur);

#pragma unroll 1
    for (int gi = 0; gi < GPW; ++gi) {
        int g = g0 + gi;
        if (g >= ngroups) break;
        int r0 = g * 16;
        f32x4 nxt[4];
        bool pf = (gi + 1 < GPW) && (g + 1 < ngroups);
        if (pf) loadA(r0 + 16, nxt);

        bf16x8 A0, A1;
        if constexpr (BF16IN) {
            A0 = __builtin_bit_cast(bf16x8, cur[0]);
            A1 = __builtin_bit_cast(bf16x8, cur[1]);
        } else {
#pragma unroll
            for (int j = 0; j < 4; ++j) {
                A0[j] = (__bf16)cur[0][j]; A0[j + 4] = (__bf16)cur[1][j];
                A1[j] = (__bf16)cur[2][j]; A1[j + 4] = (__bf16)cur[3][j];
            }
        }

        f32x4 z = {0.f, 0.f, 0.f, 0.f};
        f32x4 acc[4];
#pragma unroll
        for (int nt = 0; nt < 4; ++nt)
            acc[nt] = mfma16(A1, Bf[nt][1], mfma16(A0, Bf[nt][0], z));

        f32x4 d4 = *(const f32x4*)(dinv + r0 + q * 4);
#pragma unroll
        for (int nt = 0; nt < 4; ++nt)
#pragma unroll
            for (int reg = 0; reg < 4; ++reg) {
                int row = r0 + q * 4 + reg;
                if (row < n)
                    h[(size_t)row * DIM + nt * 16 + t] =
                        (__bf16)(acc[nt][reg] * d4[reg]);
            }
#pragma unroll
        for (int i = 0; i < 4; ++i) cur[i] = nxt[i];
    }
}

// out[node] = b + dinv[node] * (h'[node] + sum_s h'[s])
// Wide-gather version: wave = 4 groups x 16 lanes; each lane reads ushort4
// (8 B), so ONE VMEM instruction fetches 4 different src rows (4 x 128 B).
// Self row folded in as virtual edge index beg-1. 2x unroll -> 8 rows
// (1 KB) in flight per wave; avg node (deg+self ~ 7) finishes gathers in
// one issue round (vs ~3 serial rounds before).
template <typename OutT>
__global__ __launch_bounds__(256) void agg_kernel(
    const int* __restrict__ rowptr, const int* __restrict__ srcs,
    const __bf16* __restrict__ h, const float* __restrict__ bias,
    const float* __restrict__ dinv, OutT* __restrict__ out, int n) {
    int lane = threadIdx.x & 63;
    int grp = lane >> 4;        // which of 4 rows in the wide batch
    int t4 = lane & 15;         // dim quarter: dims t4*4 .. t4*4+3
    int node = blockIdx.x * 4 + __builtin_amdgcn_readfirstlane(threadIdx.x >> 6);
    if (node >= n) return;
    int beg = rowptr[node], end = rowptr[node + 1];

    float a0 = 0.f, a1 = 0.f, a2 = 0.f, a3 = 0.f;
    for (int base = beg - 1; base < end; base += 8) {
        int i0 = base + grp;
        int i1 = i0 + 4;
        int s0 = node;                       // i0 == beg-1 -> self row
        if (i0 >= beg && i0 < end) s0 = srcs[i0];
        int s1 = 0;
        if (i1 < end) s1 = srcs[i1];
        ushort4 v0 = make_ushort4(0, 0, 0, 0);
        ushort4 v1 = make_ushort4(0, 0, 0, 0);
        if (i0 < end)
            v0 = *(const ushort4*)(h + (size_t)s0 * DIM + t4 * 4);
        if (i1 < end)
            v1 = *(const ushort4*)(h + (size_t)s1 * DIM + t4 * 4);
        a0 += bf2f(v0.x) + bf2f(v1.x);
        a1 += bf2f(v0.y) + bf2f(v1.y);
        a2 += bf2f(v0.z) + bf2f(v1.z);
        a3 += bf2f(v0.w) + bf2f(v1.w);
    }
    // reduce the 4 groups: butterfly over lane bits 16 and 32
#pragma unroll
    for (int off = 16; off <= 32; off <<= 1) {
        a0 += __shfl_xor(a0, off);
        a1 += __shfl_xor(a1, off);
        a2 += __shfl_xor(a2, off);
        a3 += __shfl_xor(a3, off);
    }
    float dn = dinv[node];
    f32x4 bv = *(const f32x4*)(bias + t4 * 4);
    float r0 = fmaf(dn, a0, bv[0]);
    float r1 = fmaf(dn, a1, bv[1]);
    float r2 = fmaf(dn, a2, bv[2]);
    float r3 = fmaf(dn, a3, bv[3]);
    if (grp == 0) {
        if constexpr (sizeof(OutT) == 4) {
            f32x4 r = {r0, r1, r2, r3};
            *(f32x4*)((float*)out + (size_t)node * DIM + t4 * 4) = r;
        } else {
            bf16x4 r;
            r[0] = (__bf16)r0; r[1] = (__bf16)r1;
            r[2] = (__bf16)r2; r[3] = (__bf16)r3;
            *(bf16x4*)((__bf16*)out + (size_t)node * DIM + t4 * 4) = r;
        }
    }
}

static inline size_t align16(size_t x) { return (x + 15) & ~(size_t)15; }

extern "C" void kernel_launch(void* const* d_in, const int* in_sizes, int n_in,
                              void* d_out, int out_size, void* d_ws, size_t ws_size,
                              hipStream_t stream) {
    const int* ei         = (const int*)d_in[0];
    const float* user_emb = (const float*)d_in[1];
    const float* item_emb = (const float*)d_in[2];
    const float* W1 = (const float*)d_in[3];
    const float* b1 = (const float*)d_in[4];
    const float* W2 = (const float*)d_in[5];
    const float* b2 = (const float*)d_in[6];
    float* out = (float*)d_out;

    const int E_ = in_sizes[0] / 2;
    const int NU = in_sizes[1] / DIM;
    const int NI = in_sizes[2] / DIM;
    const int N_ = NU + NI;
    const int NB = (N_ + BSPAN - 1) >> BSHIFT;   // 391 for N=200000 (<= MAXNB)

    // workspace layout (16B-aligned)
    char* p = (char*)d_ws;
    int* srcs   = (int*)p;                   p += align16((size_t)E_ * 4);
    __bf16* h   = (__bf16*)p;                p += align16((size_t)N_ * DIM * 2);
    __bf16* t1  = (__bf16*)p;                p += align16((size_t)N_ * DIM * 2);
    float* dinv = (float*)p;                 p += align16((size_t)N_ * 4);
    int* rowptr = (int*)p;                   p += align16((size_t)(N_ + 1) * 4);
    int* bcnt   = (int*)p;                   p += align16((size_t)MAXNB * 4);
    int* bptr   = (int*)p;                   p += align16((size_t)(MAXNB + 1) * 4);
    int* bcur   = (int*)p;                   p += align16((size_t)MAXNB * 4);
    // packed edge buffer aliases t1: fully consumed by bucket_sort before
    // agg1 writes t1.
    unsigned* packed = (unsigned*)t1;

    zerob_kernel<<<1, MAXNB, 0, stream>>>(bcnt);
    bucket_count_kernel<<<256, 512, 0, stream>>>(ei, bcnt, E_, NB);
    bucket_scan_kernel<<<1, 512, 0, stream>>>(bcnt, bptr, bcur, rowptr, NB, N_, E_);
    scatter_kernel<<<256, 512, 0, stream>>>(ei, bcur, packed, E_, NB);
    bucket_sort_kernel<<<NB, 256, 0, stream>>>(packed, bptr, rowptr, srcs, dinv, N_);

    int NG = (N_ + 15) / 16;                       // 16-row groups
    int gblocks = (NG + 4 * GPW - 1) / (4 * GPW);  // 4 waves/block
    int ablocks = (N_ + 3) / 4;

    // layer 1
    gemm_kernel<false><<<gblocks, 256, 0, stream>>>(user_emb, item_emb, NU,
                                                    W1, dinv, h, N_, NG);
    agg_kernel<__bf16><<<ablocks, 256, 0, stream>>>(rowptr, srcs, h, b1, dinv, t1, N_);
    // layer 2
    gemm_kernel<true><<<gblocks, 256, 0, stream>>>(t1, t1, N_,
                                                   W2, dinv, h, N_, NG);
    agg_kernel<float><<<ablocks, 256, 0, stream>>>(rowptr, srcs, h, b2, dinv, out, N_);
}